// Round 1
// baseline (869.717 us; speedup 1.0000x reference)
//
#include <hip/hip_runtime.h>
#include <cstdint>
#include <cstddef>

#define RANK 10

// 64 rows per block, 256 threads (4 waves). Wave w handles feature quarter w.
// LDS x-tile: [64 rows][128 feat] at row stride 129 (odd -> conflict-free b32
// reads: bank = (lane*129 + f) % 32 = (lane + f) % 32 covers all banks).
__global__ __launch_bounds__(256, 4)
void cp_fusion_kernel(const float* __restrict__ x1, const float* __restrict__ x2,
                      const float* __restrict__ x3, const float* __restrict__ f1,
                      const float* __restrict__ f2, const float* __restrict__ f3,
                      const float* __restrict__ fo, float* __restrict__ out)
{
    __shared__ float lds[8320];            // 33,280 B: tile 64*129=8256; reused
                                           // as yp[4][64][30] (7680) + y[64][10]
    const int tid  = threadIdx.x;
    const int lane = tid & 63;
    const int wid  = __builtin_amdgcn_readfirstlane(tid >> 6);   // force uniform
    const int row_base = blockIdx.x << 6;  // 1024 blocks * 64 rows = 65536 exact

    const float* xs[3] = {x1, x2, x3};
    const float* fs[3] = {f1, f2, f3};
    const int    S [3] = {1024, 512, 768};
    const int    NC[3] = {8, 4, 6};        // 128-feature chunks per input

    float res[3][RANK];

    #pragma unroll
    for (int a = 0; a < 3; ++a) {
        const float* __restrict__ xa = xs[a];
        const float* __restrict__ fa = fs[a];
        const int stride = S[a];

        float acc[RANK];
        #pragma unroll
        for (int r = 0; r < RANK; ++r) acc[r] = 0.f;

        #pragma unroll 1                   // keep code size in check (I$)
        for (int c = 0; c < NC[a]; ++c) {
            const int jbase = c << 7;
            __syncthreads();               // previous tile fully consumed
            // ---- stage 64x128 tile: coalesced 4B loads, stride-1 LDS writes
            #pragma unroll
            for (int i = 0; i < 32; ++i) {
                const int e   = tid + (i << 8);
                const int row = e >> 7;
                const int col = e & 127;
                lds[row * 129 + col] =
                    xa[(size_t)(row_base + row) * stride + jbase + col];
            }
            __syncthreads();
            // ---- compute: wave wid covers features [jbase+wid*32, +32)
            const float* __restrict__ fptr = fa + (size_t)(jbase + wid * 32) * RANK;
            const float* __restrict__ xrow = &lds[lane * 129 + wid * 32];
            #pragma unroll
            for (int k = 0; k < 32; ++k) {
                const float xv = xrow[k];               // ds_read_b32, no conflict
                #pragma unroll
                for (int r = 0; r < RANK; ++r)          // factor via s_load (uniform)
                    acc[r] = fmaf(xv, fptr[k * RANK + r], acc[r]);
            }
        }
        #pragma unroll
        for (int r = 0; r < RANK; ++r) res[a][r] = acc[r];
    }

    // ---- cross-wave reduction + Hadamard product (once per block) ----
    __syncthreads();                       // x-tile dead; reuse LDS
    {
        const int pb = wid * 1920 + lane * 30;
        #pragma unroll
        for (int r = 0; r < RANK; ++r) {
            lds[pb + r]      = res[0][r];
            lds[pb + 10 + r] = res[1][r];
            lds[pb + 20 + r] = res[2][r];
        }
    }
    __syncthreads();
    if (tid < 64) {
        #pragma unroll
        for (int r = 0; r < RANK; ++r) {
            float va = 0.f, vb = 0.f, vc = 0.f;
            #pragma unroll
            for (int w = 0; w < 4; ++w) {
                const int pb = w * 1920 + tid * 30;
                va += lds[pb + r];
                vb += lds[pb + 10 + r];
                vc += lds[pb + 20 + r];
            }
            lds[7680 + tid * RANK + r] = va * vb * vc;   // y[row][r]
        }
    }
    __syncthreads();

    // ---- epilogue: out[64][512] = y[64][10] @ fo^T ----
    // Each thread owns 4 output columns; fo rows cached in 40 VGPRs.
    const int o0 = (tid & 127) << 2;
    float fo_reg[4][RANK];
    #pragma unroll
    for (int d = 0; d < 4; ++d)
        #pragma unroll
        for (int r = 0; r < RANK; ++r)
            fo_reg[d][r] = fo[(size_t)(o0 + d) * RANK + r];

    const float* y = lds + 7680;
    const int half = tid >> 7;             // waves 0,1 -> even row; 2,3 -> odd
    #pragma unroll 2
    for (int i = 0; i < 32; ++i) {
        const int row = (i << 1) + half;   // wave-uniform -> y reads broadcast
        float yv[RANK];
        #pragma unroll
        for (int r = 0; r < RANK; ++r) yv[r] = y[row * RANK + r];
        float4 o; o.x = 0.f; o.y = 0.f; o.z = 0.f; o.w = 0.f;
        #pragma unroll
        for (int r = 0; r < RANK; ++r) {
            o.x = fmaf(yv[r], fo_reg[0][r], o.x);
            o.y = fmaf(yv[r], fo_reg[1][r], o.y);
            o.z = fmaf(yv[r], fo_reg[2][r], o.z);
            o.w = fmaf(yv[r], fo_reg[3][r], o.w);
        }
        *(float4*)&out[(size_t)(row_base + row) * 512 + o0] = o;   // coalesced 16B
    }
}

extern "C" void kernel_launch(void* const* d_in, const int* in_sizes, int n_in,
                              void* d_out, int out_size, void* d_ws, size_t ws_size,
                              hipStream_t stream) {
    const float* x1 = (const float*)d_in[0];
    const float* x2 = (const float*)d_in[1];
    const float* x3 = (const float*)d_in[2];
    const float* f1 = (const float*)d_in[3];
    const float* f2 = (const float*)d_in[4];
    const float* f3 = (const float*)d_in[5];
    const float* fo = (const float*)d_in[6];
    float* out = (float*)d_out;
    (void)in_sizes; (void)n_in; (void)out_size; (void)d_ws; (void)ws_size;

    dim3 grid(1024), block(256);
    hipLaunchKernelGGL(cp_fusion_kernel, grid, block, 0, stream,
                       x1, x2, x3, f1, f2, f3, fo, out);
}

// Round 2
// 633.320 us; speedup vs baseline: 1.3733x; 1.3733x over previous
//
#include <hip/hip_runtime.h>
#include <cstdint>
#include <cstddef>

#define RANK 10

typedef float f2_t __attribute__((ext_vector_type(2)));
typedef float f4_t __attribute__((ext_vector_type(4)));

// 64 rows/block, 256 threads (4 waves). Wave w handles feature slice
// [w*32, w*32+32) of each 128-wide chunk; partial rank-sums combined in LDS.
// LDS x-tile: [64 rows][130] (pad +2 -> 8B-aligned f2 ops, 2-way bank alias = free).
__global__ __launch_bounds__(256, 4)
void cp_fusion_kernel(const float* __restrict__ x1, const float* __restrict__ x2,
                      const float* __restrict__ x3, const float* __restrict__ f1,
                      const float* __restrict__ f2, const float* __restrict__ f3,
                      const float* __restrict__ fo, float* __restrict__ out)
{
    __shared__ float lds[8320];            // tile 64*130; reused as partials+y
    const int tid  = threadIdx.x;
    const int lane = tid & 63;
    const int wid  = __builtin_amdgcn_readfirstlane(tid >> 6);
    const int row_base = blockIdx.x << 6;  // 1024 blocks * 64 rows

    const float* xs[3] = {x1, x2, x3};
    const float* fs[3] = {f1, f2, f3};
    const int    S [3] = {1024, 512, 768};
    const int    NC[3] = {8, 4, 6};

    float res[3][RANK];

    #pragma unroll
    for (int a = 0; a < 3; ++a) {
        const float* __restrict__ xa = xs[a];
        const float* __restrict__ fa = fs[a];
        const int stride = S[a];
        const int nc = NC[a];

        float acc[RANK];
        #pragma unroll
        for (int r = 0; r < RANK; ++r) acc[r] = 0.f;

        // ---- register-prefetch chunk 0 (16 x float2 per thread, coalesced)
        f2_t xpre[16];
        #pragma unroll
        for (int i = 0; i < 16; ++i) {
            const int e   = tid + (i << 8);
            const int row = e >> 6;
            const int col = (e & 63) << 1;
            xpre[i] = *(const f2_t*)&xa[(size_t)(row_base + row) * stride + col];
        }

        #pragma unroll 1
        for (int c = 0; c < nc; ++c) {
            __syncthreads();               // previous tile fully consumed
            // ---- drain prefetch regs into LDS
            #pragma unroll
            for (int i = 0; i < 16; ++i) {
                const int e   = tid + (i << 8);
                const int row = e >> 6;
                const int col = (e & 63) << 1;
                *(f2_t*)&lds[row * 130 + col] = xpre[i];
            }
            // ---- issue chunk c+1 loads now; they fly during compute
            if (c + 1 < nc) {
                const int jb = (c + 1) << 7;
                #pragma unroll
                for (int i = 0; i < 16; ++i) {
                    const int e   = tid + (i << 8);
                    const int row = e >> 6;
                    const int col = (e & 63) << 1;
                    xpre[i] = *(const f2_t*)&xa[(size_t)(row_base + row) * stride + jb + col];
                }
            }
            __syncthreads();               // tile ready

            // ---- compute: k-pairs, factors batched 5xfloat4 (80B = 2 rows),
            //      double-buffered so loads for kp+1 fly during FMAs of kp.
            const float* __restrict__ fptr = fa + (size_t)((c << 7) + wid * 32) * RANK;
            const float* __restrict__ xrow = &lds[lane * 130 + wid * 32];

            f4_t fb[2][5];
            #pragma unroll
            for (int p = 0; p < 5; ++p) fb[0][p] = *(const f4_t*)&fptr[p * 4];

            #pragma unroll
            for (int kp = 0; kp < 16; ++kp) {
                const int cur = kp & 1;
                if (kp < 15) {
                    const float* __restrict__ fnx = fptr + (kp + 1) * 20;
                    #pragma unroll
                    for (int p = 0; p < 5; ++p) fb[cur ^ 1][p] = *(const f4_t*)&fnx[p * 4];
                }
                const f2_t xv = *(const f2_t*)&xrow[kp << 1];
                const f4_t b0 = fb[cur][0], b1 = fb[cur][1], b2 = fb[cur][2],
                           b3 = fb[cur][3], b4 = fb[cur][4];
                // k0 = 2kp: ranks 0..9 = {b0.xyzw, b1.xyzw, b2.xy}
                acc[0] = fmaf(xv.x, b0.x, acc[0]);
                acc[1] = fmaf(xv.x, b0.y, acc[1]);
                acc[2] = fmaf(xv.x, b0.z, acc[2]);
                acc[3] = fmaf(xv.x, b0.w, acc[3]);
                acc[4] = fmaf(xv.x, b1.x, acc[4]);
                acc[5] = fmaf(xv.x, b1.y, acc[5]);
                acc[6] = fmaf(xv.x, b1.z, acc[6]);
                acc[7] = fmaf(xv.x, b1.w, acc[7]);
                acc[8] = fmaf(xv.x, b2.x, acc[8]);
                acc[9] = fmaf(xv.x, b2.y, acc[9]);
                // k1 = 2kp+1: ranks 0..9 = {b2.zw, b3.xyzw, b4.xyzw}
                acc[0] = fmaf(xv.y, b2.z, acc[0]);
                acc[1] = fmaf(xv.y, b2.w, acc[1]);
                acc[2] = fmaf(xv.y, b3.x, acc[2]);
                acc[3] = fmaf(xv.y, b3.y, acc[3]);
                acc[4] = fmaf(xv.y, b3.z, acc[4]);
                acc[5] = fmaf(xv.y, b3.w, acc[5]);
                acc[6] = fmaf(xv.y, b4.x, acc[6]);
                acc[7] = fmaf(xv.y, b4.y, acc[7]);
                acc[8] = fmaf(xv.y, b4.z, acc[8]);
                acc[9] = fmaf(xv.y, b4.w, acc[9]);
            }
        }
        #pragma unroll
        for (int r = 0; r < RANK; ++r) res[a][r] = acc[r];
    }

    // ---- cross-wave reduction + Hadamard product ----
    __syncthreads();                       // x-tile dead; reuse LDS
    {
        const int pb = wid * 1920 + lane * 30;
        #pragma unroll
        for (int r = 0; r < RANK; ++r) {
            lds[pb + r]      = res[0][r];
            lds[pb + 10 + r] = res[1][r];
            lds[pb + 20 + r] = res[2][r];
        }
    }
    __syncthreads();
    if (tid < 64) {
        #pragma unroll
        for (int r = 0; r < RANK; ++r) {
            float va = 0.f, vb = 0.f, vc = 0.f;
            #pragma unroll
            for (int w = 0; w < 4; ++w) {
                const int pb = w * 1920 + tid * 30;
                va += lds[pb + r];
                vb += lds[pb + 10 + r];
                vc += lds[pb + 20 + r];
            }
            lds[7680 + tid * RANK + r] = va * vb * vc;   // y[row][r]
        }
    }
    __syncthreads();

    // ---- epilogue: out[64][512] = y[64][10] @ fo^T ----
    const int o0 = (tid & 127) << 2;       // 4 output cols per thread
    const f4_t* __restrict__ fo4 = (const f4_t*)(fo + (size_t)o0 * RANK);
    f4_t fof[10];                          // 40 floats = 4 fo rows, batched loads
    #pragma unroll
    for (int p = 0; p < 10; ++p) fof[p] = fo4[p];

    const float* y = lds + 7680;
    const int half = tid >> 7;             // waves 0,1 -> even rows; 2,3 -> odd
    #pragma unroll 2
    for (int i = 0; i < 32; ++i) {
        const int row = (i << 1) + half;   // wave-uniform -> y reads broadcast
        float yv[RANK];
        #pragma unroll
        for (int r = 0; r < RANK; ++r) yv[r] = y[row * RANK + r];
        float4 o; o.x = 0.f; o.y = 0.f; o.z = 0.f; o.w = 0.f;
        #pragma unroll
        for (int d = 0; d < 4; ++d) {
            float s = 0.f;
            #pragma unroll
            for (int r = 0; r < RANK; ++r) {
                const int q = d * RANK + r;
                s = fmaf(yv[r], fof[q >> 2][q & 3], s);
            }
            if (d == 0) o.x = s; else if (d == 1) o.y = s;
            else if (d == 2) o.z = s; else o.w = s;
        }
        *(float4*)&out[(size_t)(row_base + row) * 512 + o0] = o;   // coalesced 16B
    }
}

extern "C" void kernel_launch(void* const* d_in, const int* in_sizes, int n_in,
                              void* d_out, int out_size, void* d_ws, size_t ws_size,
                              hipStream_t stream) {
    const float* x1 = (const float*)d_in[0];
    const float* x2 = (const float*)d_in[1];
    const float* x3 = (const float*)d_in[2];
    const float* f1 = (const float*)d_in[3];
    const float* f2 = (const float*)d_in[4];
    const float* f3 = (const float*)d_in[5];
    const float* fo = (const float*)d_in[6];
    float* out = (float*)d_out;
    (void)in_sizes; (void)n_in; (void)out_size; (void)d_ws; (void)ws_size;

    dim3 grid(1024), block(256);
    hipLaunchKernelGGL(cp_fusion_kernel, grid, block, 0, stream,
                       x1, x2, x3, f1, f2, f3, fo, out);
}